// Round 16
// baseline (209.321 us; speedup 1.0000x reference)
//
#include <hip/hip_runtime.h>
#include <hip/hip_bf16.h>
#include <stdint.h>

#define NNODES 100000
#define NEDGES 600000
#define SCAN_CHUNK 1024
#define SCAN_NB 98  // ceil(100000/1024)

typedef __attribute__((ext_vector_type(8))) short bf16x8;
typedef __attribute__((ext_vector_type(4))) float f32x4;
typedef __attribute__((ext_vector_type(4))) unsigned int u32x4;

__device__ inline float b2f(short b) {
    union { unsigned u; float f; } v;
    v.u = ((unsigned)(unsigned short)b) << 16;
    return v.f;
}
__device__ inline short f2b(float f) {
    union { float f; unsigned u; } v;
    v.f = f;
    unsigned r = (v.u + 0x7FFFu + ((v.u >> 16) & 1u)) >> 16;
    return (short)r;
}
__device__ inline unsigned packbf(float lo, float hi) {
    return ((unsigned)(unsigned short)f2b(hi) << 16) | (unsigned)(unsigned short)f2b(lo);
}
// accumulate one u32 of 2 bf16 into two f32 (lo: <<16, hi: mask — 4 VALU ops)
__device__ inline void accw(float& a, float& b, unsigned w) {
    union { unsigned u; float f; } x, y;
    x.u = w << 16;
    y.u = w & 0xFFFF0000u;
    a += x.f;
    b += y.f;
}
// LDS XOR swizzle for row-major [row][256B] bf16 tiles
__device__ inline int swz(int row, int kbyte) {
    return (row * 256 + kbyte) ^ ((row & 7) << 4);
}
#define MFMA16(a, b, c) __builtin_amdgcn_mfma_f32_16x16x32_bf16(a, b, c, 0, 0, 0)

// async global->LDS linear copy: n iters of 4KB (256 threads x 16B).
__device__ inline void stage_lds(const short* __restrict__ g, short* s, int w, int l, int n) {
#pragma unroll
    for (int i = 0; i < n; ++i) {
        int base = i * 4096 + w * 1024;
        __builtin_amdgcn_global_load_lds(
            (const __attribute__((address_space(1))) void*)((const char*)g + base + l * 16),
            (__attribute__((address_space(3))) void*)((char*)s + base), 16, 0, 0);
    }
}

// ---------------- fused prep ----------------
__global__ __launch_bounds__(256) void k_prep(const float* __restrict__ x,
                                              const float* __restrict__ W1,
                                              const float* __restrict__ W2,
                                              const float* __restrict__ Wm1,
                                              const float* __restrict__ Wm2,
                                              short* __restrict__ xb, short* __restrict__ Wt,
                                              int* __restrict__ cnt, float* __restrict__ stats) {
    int i = blockIdx.x * 256 + threadIdx.x;
    if (i < (NNODES + 1) * 16) {
        bf16x8 o = (bf16x8){0, 0, 0, 0, 0, 0, 0, 0};
        if (i < NNODES * 16) {
            const float4* p = (const float4*)(x + (size_t)i * 8);
            float4 a = p[0], b = p[1];
            o[0] = f2b(a.x); o[1] = f2b(a.y); o[2] = f2b(a.z); o[3] = f2b(a.w);
            o[4] = f2b(b.x); o[5] = f2b(b.y); o[6] = f2b(b.z); o[7] = f2b(b.w);
        }
        *(bf16x8*)(xb + (size_t)i * 8) = o;
    }
    if (i < NNODES) cnt[i] = 0;
    if (i < 57344) {
        int jj, lane, kt, ct;
        const float* W;
        int ldw, off;
        if (i < 16384) { off = i; W = W1; ldw = 128; }
        else if (i < 32768) { off = i - 16384; W = W2; ldw = 128; }
        else if (i < 49152) { off = i - 32768; W = Wm1; ldw = 128; }
        else { off = i - 49152; W = Wm2; ldw = 64; }
        jj = off & 7;
        lane = (off >> 3) & 63;
        kt = (off >> 9) & 3;
        ct = (off >> 11) & 7;
        int lr = lane & 15, hi = lane >> 4;
        int c = ct * 16 + lr;
        int k = kt * 32 + hi * 8 + jj;
        Wt[i] = f2b(W[k * ldw + c]);
    }
    if (i < 256) stats[i] = 0.0f;
}

// ---------------- CSR build ----------------

__global__ __launch_bounds__(256) void k_hist(const int* __restrict__ ei, int* __restrict__ cnt) {
    int e = blockIdx.x * 256 + threadIdx.x;
    if (e < NEDGES) atomicAdd(&cnt[ei[NEDGES + e]], 1);
}

// single-pass scan: each block parallel-reduces the FULL preceding prefix itself
// (<=99k coalesced int reads, L2-resident), then local Hillis-Steele chunk scan.
// cnt is read-only here (separate buffer) -> no cross-block in-place race.
__global__ __launch_bounds__(256) void k_scan(const int* __restrict__ cnt,
                                              int* __restrict__ rowptr, int* __restrict__ pos) {
    __shared__ int sd[256];
    int b = blockIdx.x, t = threadIdx.x;
    // 1) base_total = sum cnt[0 .. b*1024)
    int lim = b * SCAN_CHUNK;
    int s = 0;
    for (int idx = t; idx < lim; idx += 256) s += cnt[idx];
    sd[t] = s;
    __syncthreads();
    for (int off = 128; off > 0; off >>= 1) {
        if (t < off) sd[t] += sd[t + off];
        __syncthreads();
    }
    int base_total = sd[0];
    __syncthreads();
    // 2) local chunk scan
    int base = b * SCAN_CHUNK + t * 4;
    int v[4];
    int ls = 0;
#pragma unroll
    for (int i = 0; i < 4; ++i) {
        int idx = base + i;
        v[i] = (idx < NNODES) ? cnt[idx] : 0;
        ls += v[i];
    }
    sd[t] = ls;
    __syncthreads();
    for (int off = 1; off < 256; off <<= 1) {
        int val = (t >= off) ? sd[t - off] : 0;
        __syncthreads();
        sd[t] += val;
        __syncthreads();
    }
    int run = sd[t] - ls + base_total;
#pragma unroll
    for (int i = 0; i < 4; ++i) {
        int idx = base + i;
        if (idx < NNODES) {
            rowptr[idx] = run;
            pos[idx] = run;
            run += v[i];
        }
    }
    if (b == SCAN_NB - 1 && t == 255) rowptr[NNODES] = base_total + sd[255];
}

__global__ __launch_bounds__(256) void k_fill(const int* __restrict__ ei, int* __restrict__ pos,
                                              int* __restrict__ elist) {
    int e = blockIdx.x * 256 + threadIdx.x;
    if (e >= NEDGES) return;
    int src = ei[e];
    int dst = ei[NEDGES + e];
    int p = atomicAdd(&pos[dst], 1);
    elist[p] = src;
}

// ---------------- fused gather-aggregate + BN stats + u-export ----------------
// 512 thr, 8 waves, 64 nodes/block, coalesced elist preload. The stats MFMA computes
// the FULL u = agg@W1 tile (needed for sumsq) — so export u to bufb; k_mlp skips its
// G1 GEMM (BN+ReLU becomes elementwise).
__global__ __launch_bounds__(512, 8) void k_aggstats(const short* __restrict__ xb,
                                                     const int* __restrict__ rowptr,
                                                     const int* __restrict__ elist,
                                                     const short* __restrict__ W1pk,
                                                     short* __restrict__ bufb,
                                                     float* __restrict__ stats) {
    __shared__ __align__(16) short tile[64 * 128];  // 16KB, swizzled rows
    __shared__ float Sred[2][2][128];               // [s/q][rowgroup][col]

    int t = threadIdx.x, w = t >> 6, lane = t & 63;
    int sub = lane & 31, half = lane >> 5;
    int node0 = blockIdx.x * 64;
    int nb = node0 + w * 8;
    const uint2* xr = (const uint2*)xb;

    // coalesced rowptr read: lanes 0..8 hold rowptr[nb..nb+8]
    int vr = rowptr[min(nb + min(lane, 8), NNODES)];
    int beg_all = __shfl(vr, 0);
    int tot_e = __shfl(vr, 8) - beg_all;

    int o_i[8], t_i[8];
#pragma unroll
    for (int i = 0; i < 8; ++i) {
        int beg = __shfl(vr, i);
        int end = __shfl(vr, i + 1);
        o_i[i] = beg - beg_all;
        t_i[i] = end - beg + 1;
    }

    if (tot_e <= 128) {
        // ---- fast path: register-resident edge window ----
        int ej0 = (lane < tot_e) ? elist[beg_all + lane] : NNODES;
        int ej1 = (64 + lane < tot_e) ? elist[beg_all + 64 + lane] : NNODES;
#pragma unroll
        for (int i = 0; i < 8; ++i) {
            int n = nb + i;
            int total = t_i[i];
            float a0 = 0.f, a1 = 0.f, a2 = 0.f, a3 = 0.f;
            for (int base = 0; base < total; base += 8) {
                uint2 v[4];
#pragma unroll
                for (int k = 0; k < 4; ++k) {
                    int j = base + 2 * k + half;
                    int p = o_i[i] + j - 1;
                    int s0 = __shfl(ej0, p & 63);
                    int s1 = __shfl(ej1, p & 63);
                    int src = (p < 64) ? s0 : s1;
                    src = (j == 0) ? n : src;
                    src = (j < total && n < NNODES) ? src : NNODES;
                    v[k] = xr[(size_t)src * 32 + sub];
                }
#pragma unroll
                for (int k = 0; k < 4; ++k) {
                    accw(a0, a1, v[k].x);
                    accw(a2, a3, v[k].y);
                }
            }
            a0 += __shfl_xor(a0, 32);
            a1 += __shfl_xor(a1, 32);
            a2 += __shfl_xor(a2, 32);
            a3 += __shfl_xor(a3, 32);
            if (half == 0) {
                int row = w * 8 + i;
                int b8 = sub * 8;
                int off = swz(row, b8 & ~15) + (b8 & 8);
                uint2 o;
                o.x = packbf(a0, a1);
                o.y = packbf(a2, a3);
                *(uint2*)((char*)tile + off) = o;
            }
        }
    } else {
        // ---- slow path (rare): per-node serial ----
#pragma unroll
        for (int i = 0; i < 8; ++i) {
            int n = nb + i;
            int total = t_i[i];
            int beg = beg_all + o_i[i];
            float a0 = 0.f, a1 = 0.f, a2 = 0.f, a3 = 0.f;
            if (n < NNODES) {
                for (int base = 0; base < total; base += 64) {
                    int j = base + lane;
                    int ej = NNODES;
                    if (j < total) ej = (j == 0) ? n : elist[beg + j - 1];
                    int cnt = min(64, total - base);
                    int pairs = (cnt + 1) >> 1;
                    for (int ii = 0; ii < pairs; ii += 4) {
                        int j0 = 2 * ii + half;
                        int r0 = __shfl(ej, j0);
                        int r1 = __shfl(ej, j0 + 2);
                        int r2 = __shfl(ej, j0 + 4);
                        int r3 = __shfl(ej, j0 + 6);
                        uint2 v0 = xr[(size_t)r0 * 32 + sub];
                        uint2 v1 = xr[(size_t)r1 * 32 + sub];
                        uint2 v2 = xr[(size_t)r2 * 32 + sub];
                        uint2 v3 = xr[(size_t)r3 * 32 + sub];
                        accw(a0, a1, v0.x); accw(a2, a3, v0.y);
                        accw(a0, a1, v1.x); accw(a2, a3, v1.y);
                        accw(a0, a1, v2.x); accw(a2, a3, v2.y);
                        accw(a0, a1, v3.x); accw(a2, a3, v3.y);
                    }
                }
            }
            a0 += __shfl_xor(a0, 32);
            a1 += __shfl_xor(a1, 32);
            a2 += __shfl_xor(a2, 32);
            a3 += __shfl_xor(a3, 32);
            if (half == 0) {
                int row = w * 8 + i;
                int b8 = sub * 8;
                int off = swz(row, b8 & ~15) + (b8 & 8);
                uint2 o;
                o.x = packbf(a0, a1);
                o.y = packbf(a2, a3);
                *(uint2*)((char*)tile + off) = o;
            }
        }
    }
    __syncthreads();

    // stats MFMA: wave w -> rowgroup rg = w&1 (32 rows), colgroup cg = w>>1 (32 cols)
    int lr = lane & 15, hi = lane >> 4;
    int rg = w & 1, cg = w >> 1;
    f32x4 uacc[2][2];
#pragma unroll
    for (int r = 0; r < 2; ++r)
#pragma unroll
        for (int c = 0; c < 2; ++c) uacc[r][c] = (f32x4){0.f, 0.f, 0.f, 0.f};
#pragma unroll
    for (int kb = 0; kb < 4; ++kb) {
        int kbyte = kb * 64 + hi * 16;
        bf16x8 af[2], bw[2];
#pragma unroll
        for (int r = 0; r < 2; ++r)
            af[r] = *(const bf16x8*)((char*)tile + swz(rg * 32 + r * 16 + lr, kbyte));
#pragma unroll
        for (int c = 0; c < 2; ++c)
            bw[c] = *(const bf16x8*)(W1pk + (((cg * 2 + c) * 4 + kb) * 64 + lane) * 8);
#pragma unroll
        for (int r = 0; r < 2; ++r)
#pragma unroll
            for (int c = 0; c < 2; ++c) uacc[r][c] = MFMA16(af[r], bw[c], uacc[r][c]);
    }
    {
        float s[2], q[2];
#pragma unroll
        for (int c = 0; c < 2; ++c) { s[c] = 0.f; q[c] = 0.f; }
#pragma unroll
        for (int c = 0; c < 2; ++c)
#pragma unroll
            for (int r = 0; r < 2; ++r)
#pragma unroll
                for (int rr = 0; rr < 4; ++rr) {
                    float v = uacc[r][c][rr];
                    s[c] += v;
                    q[c] += v * v;
                }
#pragma unroll
        for (int c = 0; c < 2; ++c) {
            s[c] += __shfl_xor(s[c], 16); s[c] += __shfl_xor(s[c], 32);
            q[c] += __shfl_xor(q[c], 16); q[c] += __shfl_xor(q[c], 32);
        }
        if (lane < 16) {
#pragma unroll
            for (int c = 0; c < 2; ++c) {
                int col = (cg * 2 + c) * 16 + lane;
                Sred[0][rg][col] = s[c];
                Sred[1][rg][col] = q[c];
            }
        }
    }
    __syncthreads();  // all MFMA tile reads done; Sred complete

    // overwrite tile with u (bf16); C-layout: node=rg*32+r*16+hi*4+rr, ch=(cg*2+c)*16+lr
#pragma unroll
    for (int r = 0; r < 2; ++r)
#pragma unroll
        for (int c = 0; c < 2; ++c)
#pragma unroll
            for (int rr = 0; rr < 4; ++rr) {
                int row = rg * 32 + r * 16 + hi * 4 + rr;
                int ch = (cg * 2 + c) * 16 + lr;
                int off = (row * 256 + ch * 2) ^ ((row & 7) << 4);
                *(short*)((char*)tile + off) = f2b(uacc[r][c][rr]);
            }
    if (t < 128) {
        atomicAdd(stats + t, Sred[0][0][t] + Sred[0][1][t]);
        atomicAdd(stats + 128 + t, Sred[1][0][t] + Sred[1][1][t]);
    }
    __syncthreads();  // u writes complete

    // coalesced bufb write of u from LDS
    {
        int row = t >> 3, chunk = t & 7;
        int gr = node0 + row;
        if (gr < NNODES) {
            bf16x8 c0 = *(const bf16x8*)((char*)tile + swz(row, chunk * 32));
            bf16x8 c1 = *(const bf16x8*)((char*)tile + swz(row, chunk * 32 + 16));
            *(bf16x8*)(bufb + (size_t)gr * 128 + chunk * 16) = c0;
            *(bf16x8*)(bufb + (size_t)gr * 128 + chunk * 16 + 8) = c1;
        }
    }
}

// ---------------- fused MLP (bufb holds u = agg@W1): BN elementwise, G2..G4 --------
__global__ __launch_bounds__(256, 4) void k_mlp(const short* __restrict__ bufb,
                                                const float* __restrict__ stats,
                                                const float* __restrict__ gamma,
                                                const float* __restrict__ beta,
                                                const short* __restrict__ Wt,
                                                const float* __restrict__ b2,
                                                const float* __restrict__ bm1,
                                                const float* __restrict__ bm2,
                                                float* __restrict__ out) {
    __shared__ __align__(16) short wbuf[16384];  // 32KB weight stage
    __shared__ float scl[3][128], shf[3][128], bm2s[64];

    int t = threadIdx.x, w = t >> 6, l = t & 63;
    int lr = l & 15, hi = l >> 4;
    size_t node0 = (size_t)blockIdx.x * 128 + w * 32;

    stage_lds(Wt + 16384, wbuf, w, l, 8);  // W2 first (G1 is gone)
    if (t < 128) {
        float mean = stats[t] * (1.0f / NNODES);
        float var = fmaxf(stats[128 + t] * (1.0f / NNODES) - mean * mean, 0.0f);
        float inv = rsqrtf(var + 1e-5f);
        float sc = gamma[t] * inv;
        scl[0][t] = sc;
        shf[0][t] = beta[t] - mean * sc;  // b1 cancels in batch-stats BN
        scl[1][t] = 1.0f;
        shf[1][t] = b2[t];
        scl[2][t] = 1.0f;
        shf[2][t] = bm1[t];
    }
    if (t < 64) bm2s[t] = bm2[t];

    // load u fragments (B-frag layout already: node=lr, ch=kt*32+hi*8+j)
    bf16x8 bvA[4], bvB[4];
#pragma unroll
    for (int kt = 0; kt < 4; ++kt) {
        bvA[kt] = *(const bf16x8*)(bufb + (node0 + lr) * 128 + kt * 32 + hi * 8);
        bvB[kt] = *(const bf16x8*)(bufb + (node0 + 16 + lr) * 128 + kt * 32 + hi * 8);
    }
    __syncthreads();  // W2 + tables ready

    // h1 = relu(BN(u)) — elementwise, no GEMM / no REDIST needed
#pragma unroll
    for (int kt = 0; kt < 4; ++kt) {
        bf16x8 ia = bvA[kt], ib = bvB[kt];
        bf16x8 oa, ob;
#pragma unroll
        for (int j = 0; j < 8; ++j) {
            int ch = kt * 32 + hi * 8 + j;
            float sc_ = scl[0][ch], sh_ = shf[0][ch];
            oa[j] = f2b(fmaxf(b2f(ia[j]) * sc_ + sh_, 0.f));
            ob[j] = f2b(fmaxf(b2f(ib[j]) * sc_ + sh_, 0.f));
        }
        bvA[kt] = oa;
        bvB[kt] = ob;
    }

    unsigned pwA[8][2], pwB[8][2];

    for (int g = 1; g < 3; ++g) {
#pragma unroll
        for (int ch = 0; ch < 2; ++ch) {
            f32x4 aA[4], aB[4];
#pragma unroll
            for (int cc = 0; cc < 4; ++cc) {
                aA[cc] = (f32x4){0.f, 0.f, 0.f, 0.f};
                aB[cc] = (f32x4){0.f, 0.f, 0.f, 0.f};
            }
#pragma unroll
            for (int kt = 0; kt < 4; ++kt) {
                bf16x8 wv[4];
#pragma unroll
                for (int cc = 0; cc < 4; ++cc)
                    wv[cc] = *(const bf16x8*)(wbuf + ((((ch * 4 + cc) * 4) + kt) * 64 + l) * 8);
#pragma unroll
                for (int cc = 0; cc < 4; ++cc) {
                    aA[cc] = MFMA16(wv[cc], bvA[kt], aA[cc]);
                    aB[cc] = MFMA16(wv[cc], bvB[kt], aB[cc]);
                }
            }
#pragma unroll
            for (int cc = 0; cc < 4; ++cc) {
                int ct = ch * 4 + cc;
                int c0 = ct * 16 + hi * 4;
                float4 s4 = *(const float4*)&scl[g][c0];
                float4 h4 = *(const float4*)&shf[g][c0];
                pwA[ct][0] = packbf(fmaxf(aA[cc][0] * s4.x + h4.x, 0.f),
                                    fmaxf(aA[cc][1] * s4.y + h4.y, 0.f));
                pwA[ct][1] = packbf(fmaxf(aA[cc][2] * s4.z + h4.z, 0.f),
                                    fmaxf(aA[cc][3] * s4.w + h4.w, 0.f));
                pwB[ct][0] = packbf(fmaxf(aB[cc][0] * s4.x + h4.x, 0.f),
                                    fmaxf(aB[cc][1] * s4.y + h4.y, 0.f));
                pwB[ct][1] = packbf(fmaxf(aB[cc][2] * s4.z + h4.z, 0.f),
                                    fmaxf(aB[cc][3] * s4.w + h4.w, 0.f));
            }
        }
        __syncthreads();
        if (g < 2) stage_lds(Wt + (g + 1) * 16384, wbuf, w, l, 8);  // g=1 -> Wm1
        else       stage_lds(Wt + 49152, wbuf, w, l, 4);            // g=2 -> Wm2 (16KB)

        {
            int h2 = hi >> 1, h1 = hi & 1;
#pragma unroll
            for (int kt = 0; kt < 4; ++kt) {
                unsigned nwA[4], nwB[4];
#pragma unroll
                for (int jp = 0; jp < 4; ++jp) {
                    int srcl = (2 * h1 + (jp >> 1)) * 16 + lr;
                    unsigned veA = (unsigned)__shfl((int)pwA[2 * kt][jp & 1], srcl);
                    unsigned voA = (unsigned)__shfl((int)pwA[2 * kt + 1][jp & 1], srcl);
                    unsigned veB = (unsigned)__shfl((int)pwB[2 * kt][jp & 1], srcl);
                    unsigned voB = (unsigned)__shfl((int)pwB[2 * kt + 1][jp & 1], srcl);
                    nwA[jp] = h2 ? voA : veA;
                    nwB[jp] = h2 ? voB : veB;
                }
                u32x4 uqA = (u32x4){nwA[0], nwA[1], nwA[2], nwA[3]};
                u32x4 uqB = (u32x4){nwB[0], nwB[1], nwB[2], nwB[3]};
                bvA[kt] = __builtin_bit_cast(bf16x8, uqA);
                bvB[kt] = __builtin_bit_cast(bf16x8, uqB);
            }
        }
        __syncthreads();
    }

    // ---- G4: h @ Wm2 + bm2 -> out ----
#pragma unroll
    for (int ct = 0; ct < 4; ++ct) {
        f32x4 aA = (f32x4){0.f, 0.f, 0.f, 0.f};
        f32x4 aB = (f32x4){0.f, 0.f, 0.f, 0.f};
#pragma unroll
        for (int kt = 0; kt < 4; ++kt) {
            bf16x8 wv = *(const bf16x8*)(wbuf + ((ct * 4 + kt) * 64 + l) * 8);
            aA = MFMA16(bvA[kt], wv, aA);
            aB = MFMA16(bvB[kt], wv, aB);
        }
        float bias = bm2s[ct * 16 + lr];
#pragma unroll
        for (int rr = 0; rr < 4; ++rr) {
            size_t growA = node0 + hi * 4 + rr;
            size_t growB = node0 + 16 + hi * 4 + rr;
            if (growA < NNODES) out[growA * 64 + ct * 16 + lr] = aA[rr] + bias;
            if (growB < NNODES) out[growB * 64 + ct * 16 + lr] = aB[rr] + bias;
        }
    }
}

// ---------------- launch ----------------
extern "C" void kernel_launch(void* const* d_in, const int* in_sizes, int n_in,
                              void* d_out, int out_size, void* d_ws, size_t ws_size,
                              hipStream_t stream) {
    const float* x     = (const float*)d_in[0];
    const int*   ei    = (const int*)d_in[1];
    const float* W1    = (const float*)d_in[2];
    const float* gamma = (const float*)d_in[4];
    const float* beta  = (const float*)d_in[5];
    const float* W2    = (const float*)d_in[6];
    const float* b2    = (const float*)d_in[7];
    const float* Wm1   = (const float*)d_in[8];
    const float* bm1   = (const float*)d_in[9];
    const float* Wm2   = (const float*)d_in[10];
    const float* bm2   = (const float*)d_in[11];
    float* out = (float*)d_out;

    char* ws = (char*)d_ws;
    short* xb    = (short*)ws;                           // (N+1)*128 bf16 (last row zeros)
    short* bufb  = xb + (size_t)(NNODES + 1) * 128;      // (N+128)*128 bf16 (holds u)
    short* Wt    = bufb + (size_t)(NNODES + 128) * 128;  // 57344 bf16 packed fragments
    float* stats = (float*)(Wt + 57344);                 // 256 f32
    int* rowptr  = (int*)(stats + 256);                  // N+1
    int* pos     = rowptr + (NNODES + 1);                // N (fill cursors)
    int* elist   = pos + NNODES;                         // E
    int* cnt     = elist + NEDGES;                       // N (histogram, read-only in scan)

    int gE = (NEDGES + 255) / 256;
    int gPrep = ((NNODES + 1) * 16 + 255) / 256;

    k_prep<<<gPrep, 256, 0, stream>>>(x, W1, W2, Wm1, Wm2, xb, Wt, cnt, stats);
    k_hist<<<gE, 256, 0, stream>>>(ei, cnt);
    k_scan<<<SCAN_NB, 256, 0, stream>>>(cnt, rowptr, pos);
    k_fill<<<gE, 256, 0, stream>>>(ei, pos, elist);

    int gAgg = (NNODES + 63) / 64;
    k_aggstats<<<gAgg, 512, 0, stream>>>(xb, rowptr, elist, Wt, bufb, stats);

    int nblkM = (NNODES + 127) / 128;
    k_mlp<<<nblkM, 256, 0, stream>>>(bufb, stats, gamma, beta, Wt, b2, bm1, bm2, out);
}

// Round 17
// 163.896 us; speedup vs baseline: 1.2772x; 1.2772x over previous
//
#include <hip/hip_runtime.h>
#include <hip/hip_bf16.h>
#include <stdint.h>

#define NNODES 100000
#define NEDGES 600000
#define SCAN_CHUNK 1024
#define SCAN_NB 98  // ceil(100000/1024)

typedef __attribute__((ext_vector_type(8))) short bf16x8;
typedef __attribute__((ext_vector_type(4))) float f32x4;
typedef __attribute__((ext_vector_type(4))) unsigned int u32x4;

__device__ inline float b2f(short b) {
    union { unsigned u; float f; } v;
    v.u = ((unsigned)(unsigned short)b) << 16;
    return v.f;
}
__device__ inline short f2b(float f) {
    union { float f; unsigned u; } v;
    v.f = f;
    unsigned r = (v.u + 0x7FFFu + ((v.u >> 16) & 1u)) >> 16;
    return (short)r;
}
__device__ inline unsigned packbf(float lo, float hi) {
    return ((unsigned)(unsigned short)f2b(hi) << 16) | (unsigned)(unsigned short)f2b(lo);
}
// accumulate one u32 of 2 bf16 into two f32 (lo: <<16, hi: mask — 4 VALU ops)
__device__ inline void accw(float& a, float& b, unsigned w) {
    union { unsigned u; float f; } x, y;
    x.u = w << 16;
    y.u = w & 0xFFFF0000u;
    a += x.f;
    b += y.f;
}
// LDS XOR swizzle for row-major [row][256B] bf16 tiles
__device__ inline int swz(int row, int kbyte) {
    return (row * 256 + kbyte) ^ ((row & 7) << 4);
}
#define MFMA16(a, b, c) __builtin_amdgcn_mfma_f32_16x16x32_bf16(a, b, c, 0, 0, 0)

// async global->LDS linear copy: n iters of 4KB (256 threads x 16B).
__device__ inline void stage_lds(const short* __restrict__ g, short* s, int w, int l, int n) {
#pragma unroll
    for (int i = 0; i < n; ++i) {
        int base = i * 4096 + w * 1024;
        __builtin_amdgcn_global_load_lds(
            (const __attribute__((address_space(1))) void*)((const char*)g + base + l * 16),
            (__attribute__((address_space(3))) void*)((char*)s + base), 16, 0, 0);
    }
}

// ---------------- fused prep ----------------
__global__ __launch_bounds__(256) void k_prep(const float* __restrict__ x,
                                              const float* __restrict__ W1,
                                              const float* __restrict__ W2,
                                              const float* __restrict__ Wm1,
                                              const float* __restrict__ Wm2,
                                              short* __restrict__ xb, short* __restrict__ Wt,
                                              int* __restrict__ pos, float* __restrict__ stats) {
    int i = blockIdx.x * 256 + threadIdx.x;
    if (i < (NNODES + 1) * 16) {
        bf16x8 o = (bf16x8){0, 0, 0, 0, 0, 0, 0, 0};
        if (i < NNODES * 16) {
            const float4* p = (const float4*)(x + (size_t)i * 8);
            float4 a = p[0], b = p[1];
            o[0] = f2b(a.x); o[1] = f2b(a.y); o[2] = f2b(a.z); o[3] = f2b(a.w);
            o[4] = f2b(b.x); o[5] = f2b(b.y); o[6] = f2b(b.z); o[7] = f2b(b.w);
        }
        *(bf16x8*)(xb + (size_t)i * 8) = o;
    }
    if (i < NNODES) pos[i] = 0;
    if (i < 57344) {
        int jj, lane, kt, ct;
        const float* W;
        int ldw, off;
        if (i < 16384) { off = i; W = W1; ldw = 128; }
        else if (i < 32768) { off = i - 16384; W = W2; ldw = 128; }
        else if (i < 49152) { off = i - 32768; W = Wm1; ldw = 128; }
        else { off = i - 49152; W = Wm2; ldw = 64; }
        jj = off & 7;
        lane = (off >> 3) & 63;
        kt = (off >> 9) & 3;
        ct = (off >> 11) & 7;
        int lr = lane & 15, hi = lane >> 4;
        int c = ct * 16 + lr;
        int k = kt * 32 + hi * 8 + jj;
        Wt[i] = f2b(W[k * ldw + c]);
    }
    if (i < 256) stats[i] = 0.0f;
}

// ---------------- CSR build ----------------

__global__ __launch_bounds__(256) void k_hist(const int* __restrict__ ei, int* __restrict__ cnt) {
    int e = blockIdx.x * 256 + threadIdx.x;
    if (e < NEDGES) atomicAdd(&cnt[ei[NEDGES + e]], 1);
}

// per-block sums of 1024 counts
__global__ __launch_bounds__(256) void k_scan1(const int* __restrict__ cnt, int* __restrict__ bsums) {
    __shared__ int sd[256];
    int b = blockIdx.x, t = threadIdx.x;
    int base = b * SCAN_CHUNK + t * 4;
    int s = 0;
#pragma unroll
    for (int i = 0; i < 4; ++i) {
        int idx = base + i;
        if (idx < NNODES) s += cnt[idx];
    }
    sd[t] = s;
    __syncthreads();
    for (int off = 128; off > 0; off >>= 1) {
        if (t < off) sd[t] += sd[t + off];
        __syncthreads();
    }
    if (t == 0) bsums[b] = sd[0];
}

// merged scan2+scan3: each block derives its own exclusive base from bsums (98 ints,
// parallel LDS scan — short chains only), then does the chunk scan. cnt/pos may alias
// (each thread reads its 4 values into regs before writing).
__global__ __launch_bounds__(256) void k_scan23(const int* __restrict__ cnt,
                                                const int* __restrict__ bsums,
                                                int* __restrict__ rowptr, int* __restrict__ pos) {
    __shared__ int sd[256];
    int b = blockIdx.x, t = threadIdx.x;

    // exclusive prefix of bsums via shifted inclusive scan
    int sv = (t >= 1 && t <= SCAN_NB) ? bsums[t - 1] : 0;
    sd[t] = sv;
    __syncthreads();
    for (int off = 1; off < 256; off <<= 1) {
        int val = (t >= off) ? sd[t - off] : 0;
        __syncthreads();
        sd[t] += val;
        __syncthreads();
    }
    int base_total = sd[b];  // sum of bsums[0..b)
    __syncthreads();

    // chunk scan (identical to R15 scan3)
    int base = b * SCAN_CHUNK + t * 4;
    int v[4];
    int ls = 0;
#pragma unroll
    for (int i = 0; i < 4; ++i) {
        int idx = base + i;
        v[i] = (idx < NNODES) ? cnt[idx] : 0;
        ls += v[i];
    }
    sd[t] = ls;
    __syncthreads();
    for (int off = 1; off < 256; off <<= 1) {
        int val = (t >= off) ? sd[t - off] : 0;
        __syncthreads();
        sd[t] += val;
        __syncthreads();
    }
    int run = sd[t] - ls + base_total;
#pragma unroll
    for (int i = 0; i < 4; ++i) {
        int idx = base + i;
        if (idx < NNODES) {
            rowptr[idx] = run;
            pos[idx] = run;
            run += v[i];
        }
    }
    if (b == SCAN_NB - 1 && t == 255) rowptr[NNODES] = base_total + sd[255];
}

__global__ __launch_bounds__(256) void k_fill(const int* __restrict__ ei, int* __restrict__ pos,
                                              int* __restrict__ elist) {
    int e = blockIdx.x * 256 + threadIdx.x;
    if (e >= NEDGES) return;
    int src = ei[e];
    int dst = ei[NEDGES + e];
    int p = atomicAdd(&pos[dst], 1);
    elist[p] = src;
}

// ---------------- fused gather-aggregate + BN stats + u-export ----------------
// 512 thr, 8 waves, 64 nodes/block, coalesced elist preload. The stats MFMA computes
// the FULL u = agg@W1 tile (needed for sumsq) — so export u to bufb; k_mlp skips its
// G1 GEMM (BN+ReLU becomes elementwise).
__global__ __launch_bounds__(512, 8) void k_aggstats(const short* __restrict__ xb,
                                                     const int* __restrict__ rowptr,
                                                     const int* __restrict__ elist,
                                                     const short* __restrict__ W1pk,
                                                     short* __restrict__ bufb,
                                                     float* __restrict__ stats) {
    __shared__ __align__(16) short tile[64 * 128];  // 16KB, swizzled rows
    __shared__ float Sred[2][2][128];               // [s/q][rowgroup][col]

    int t = threadIdx.x, w = t >> 6, lane = t & 63;
    int sub = lane & 31, half = lane >> 5;
    int node0 = blockIdx.x * 64;
    int nb = node0 + w * 8;
    const uint2* xr = (const uint2*)xb;

    // coalesced rowptr read: lanes 0..8 hold rowptr[nb..nb+8]
    int vr = rowptr[min(nb + min(lane, 8), NNODES)];
    int beg_all = __shfl(vr, 0);
    int tot_e = __shfl(vr, 8) - beg_all;

    int o_i[8], t_i[8];
#pragma unroll
    for (int i = 0; i < 8; ++i) {
        int beg = __shfl(vr, i);
        int end = __shfl(vr, i + 1);
        o_i[i] = beg - beg_all;
        t_i[i] = end - beg + 1;
    }

    if (tot_e <= 128) {
        // ---- fast path: register-resident edge window ----
        int ej0 = (lane < tot_e) ? elist[beg_all + lane] : NNODES;
        int ej1 = (64 + lane < tot_e) ? elist[beg_all + 64 + lane] : NNODES;
#pragma unroll
        for (int i = 0; i < 8; ++i) {
            int n = nb + i;
            int total = t_i[i];
            float a0 = 0.f, a1 = 0.f, a2 = 0.f, a3 = 0.f;
            for (int base = 0; base < total; base += 8) {
                uint2 v[4];
#pragma unroll
                for (int k = 0; k < 4; ++k) {
                    int j = base + 2 * k + half;
                    int p = o_i[i] + j - 1;
                    int s0 = __shfl(ej0, p & 63);
                    int s1 = __shfl(ej1, p & 63);
                    int src = (p < 64) ? s0 : s1;
                    src = (j == 0) ? n : src;
                    src = (j < total && n < NNODES) ? src : NNODES;
                    v[k] = xr[(size_t)src * 32 + sub];
                }
#pragma unroll
                for (int k = 0; k < 4; ++k) {
                    accw(a0, a1, v[k].x);
                    accw(a2, a3, v[k].y);
                }
            }
            a0 += __shfl_xor(a0, 32);
            a1 += __shfl_xor(a1, 32);
            a2 += __shfl_xor(a2, 32);
            a3 += __shfl_xor(a3, 32);
            if (half == 0) {
                int row = w * 8 + i;
                int b8 = sub * 8;
                int off = swz(row, b8 & ~15) + (b8 & 8);
                uint2 o;
                o.x = packbf(a0, a1);
                o.y = packbf(a2, a3);
                *(uint2*)((char*)tile + off) = o;
            }
        }
    } else {
        // ---- slow path (rare): per-node serial ----
#pragma unroll
        for (int i = 0; i < 8; ++i) {
            int n = nb + i;
            int total = t_i[i];
            int beg = beg_all + o_i[i];
            float a0 = 0.f, a1 = 0.f, a2 = 0.f, a3 = 0.f;
            if (n < NNODES) {
                for (int base = 0; base < total; base += 64) {
                    int j = base + lane;
                    int ej = NNODES;
                    if (j < total) ej = (j == 0) ? n : elist[beg + j - 1];
                    int cnt = min(64, total - base);
                    int pairs = (cnt + 1) >> 1;
                    for (int ii = 0; ii < pairs; ii += 4) {
                        int j0 = 2 * ii + half;
                        int r0 = __shfl(ej, j0);
                        int r1 = __shfl(ej, j0 + 2);
                        int r2 = __shfl(ej, j0 + 4);
                        int r3 = __shfl(ej, j0 + 6);
                        uint2 v0 = xr[(size_t)r0 * 32 + sub];
                        uint2 v1 = xr[(size_t)r1 * 32 + sub];
                        uint2 v2 = xr[(size_t)r2 * 32 + sub];
                        uint2 v3 = xr[(size_t)r3 * 32 + sub];
                        accw(a0, a1, v0.x); accw(a2, a3, v0.y);
                        accw(a0, a1, v1.x); accw(a2, a3, v1.y);
                        accw(a0, a1, v2.x); accw(a2, a3, v2.y);
                        accw(a0, a1, v3.x); accw(a2, a3, v3.y);
                    }
                }
            }
            a0 += __shfl_xor(a0, 32);
            a1 += __shfl_xor(a1, 32);
            a2 += __shfl_xor(a2, 32);
            a3 += __shfl_xor(a3, 32);
            if (half == 0) {
                int row = w * 8 + i;
                int b8 = sub * 8;
                int off = swz(row, b8 & ~15) + (b8 & 8);
                uint2 o;
                o.x = packbf(a0, a1);
                o.y = packbf(a2, a3);
                *(uint2*)((char*)tile + off) = o;
            }
        }
    }
    __syncthreads();

    // stats MFMA: wave w -> rowgroup rg = w&1 (32 rows), colgroup cg = w>>1 (32 cols)
    int lr = lane & 15, hi = lane >> 4;
    int rg = w & 1, cg = w >> 1;
    f32x4 uacc[2][2];
#pragma unroll
    for (int r = 0; r < 2; ++r)
#pragma unroll
        for (int c = 0; c < 2; ++c) uacc[r][c] = (f32x4){0.f, 0.f, 0.f, 0.f};
#pragma unroll
    for (int kb = 0; kb < 4; ++kb) {
        int kbyte = kb * 64 + hi * 16;
        bf16x8 af[2], bw[2];
#pragma unroll
        for (int r = 0; r < 2; ++r)
            af[r] = *(const bf16x8*)((char*)tile + swz(rg * 32 + r * 16 + lr, kbyte));
#pragma unroll
        for (int c = 0; c < 2; ++c)
            bw[c] = *(const bf16x8*)(W1pk + (((cg * 2 + c) * 4 + kb) * 64 + lane) * 8);
#pragma unroll
        for (int r = 0; r < 2; ++r)
#pragma unroll
            for (int c = 0; c < 2; ++c) uacc[r][c] = MFMA16(af[r], bw[c], uacc[r][c]);
    }
    {
        float s[2], q[2];
#pragma unroll
        for (int c = 0; c < 2; ++c) { s[c] = 0.f; q[c] = 0.f; }
#pragma unroll
        for (int c = 0; c < 2; ++c)
#pragma unroll
            for (int r = 0; r < 2; ++r)
#pragma unroll
                for (int rr = 0; rr < 4; ++rr) {
                    float v = uacc[r][c][rr];
                    s[c] += v;
                    q[c] += v * v;
                }
#pragma unroll
        for (int c = 0; c < 2; ++c) {
            s[c] += __shfl_xor(s[c], 16); s[c] += __shfl_xor(s[c], 32);
            q[c] += __shfl_xor(q[c], 16); q[c] += __shfl_xor(q[c], 32);
        }
        if (lane < 16) {
#pragma unroll
            for (int c = 0; c < 2; ++c) {
                int col = (cg * 2 + c) * 16 + lane;
                Sred[0][rg][col] = s[c];
                Sred[1][rg][col] = q[c];
            }
        }
    }
    __syncthreads();  // all MFMA tile reads done; Sred complete

    // overwrite tile with u (bf16); C-layout: node=rg*32+r*16+hi*4+rr, ch=(cg*2+c)*16+lr
#pragma unroll
    for (int r = 0; r < 2; ++r)
#pragma unroll
        for (int c = 0; c < 2; ++c)
#pragma unroll
            for (int rr = 0; rr < 4; ++rr) {
                int row = rg * 32 + r * 16 + hi * 4 + rr;
                int ch = (cg * 2 + c) * 16 + lr;
                int off = (row * 256 + ch * 2) ^ ((row & 7) << 4);
                *(short*)((char*)tile + off) = f2b(uacc[r][c][rr]);
            }
    if (t < 128) {
        atomicAdd(stats + t, Sred[0][0][t] + Sred[0][1][t]);
        atomicAdd(stats + 128 + t, Sred[1][0][t] + Sred[1][1][t]);
    }
    __syncthreads();  // u writes complete

    // coalesced bufb write of u from LDS
    {
        int row = t >> 3, chunk = t & 7;
        int gr = node0 + row;
        if (gr < NNODES) {
            bf16x8 c0 = *(const bf16x8*)((char*)tile + swz(row, chunk * 32));
            bf16x8 c1 = *(const bf16x8*)((char*)tile + swz(row, chunk * 32 + 16));
            *(bf16x8*)(bufb + (size_t)gr * 128 + chunk * 16) = c0;
            *(bf16x8*)(bufb + (size_t)gr * 128 + chunk * 16 + 8) = c1;
        }
    }
}

// ---------------- fused MLP (bufb holds u = agg@W1): BN elementwise, G2..G4 --------
__global__ __launch_bounds__(256, 4) void k_mlp(const short* __restrict__ bufb,
                                                const float* __restrict__ stats,
                                                const float* __restrict__ gamma,
                                                const float* __restrict__ beta,
                                                const short* __restrict__ Wt,
                                                const float* __restrict__ b2,
                                                const float* __restrict__ bm1,
                                                const float* __restrict__ bm2,
                                                float* __restrict__ out) {
    __shared__ __align__(16) short wbuf[16384];  // 32KB weight stage
    __shared__ float scl[3][128], shf[3][128], bm2s[64];

    int t = threadIdx.x, w = t >> 6, l = t & 63;
    int lr = l & 15, hi = l >> 4;
    size_t node0 = (size_t)blockIdx.x * 128 + w * 32;

    stage_lds(Wt + 16384, wbuf, w, l, 8);  // W2 first (G1 is gone)
    if (t < 128) {
        float mean = stats[t] * (1.0f / NNODES);
        float var = fmaxf(stats[128 + t] * (1.0f / NNODES) - mean * mean, 0.0f);
        float inv = rsqrtf(var + 1e-5f);
        float sc = gamma[t] * inv;
        scl[0][t] = sc;
        shf[0][t] = beta[t] - mean * sc;  // b1 cancels in batch-stats BN
        scl[1][t] = 1.0f;
        shf[1][t] = b2[t];
        scl[2][t] = 1.0f;
        shf[2][t] = bm1[t];
    }
    if (t < 64) bm2s[t] = bm2[t];

    // load u fragments (B-frag layout already: node=lr, ch=kt*32+hi*8+j)
    bf16x8 bvA[4], bvB[4];
#pragma unroll
    for (int kt = 0; kt < 4; ++kt) {
        bvA[kt] = *(const bf16x8*)(bufb + (node0 + lr) * 128 + kt * 32 + hi * 8);
        bvB[kt] = *(const bf16x8*)(bufb + (node0 + 16 + lr) * 128 + kt * 32 + hi * 8);
    }
    __syncthreads();  // W2 + tables ready

    // h1 = relu(BN(u)) — elementwise, no GEMM / no REDIST needed
#pragma unroll
    for (int kt = 0; kt < 4; ++kt) {
        bf16x8 ia = bvA[kt], ib = bvB[kt];
        bf16x8 oa, ob;
#pragma unroll
        for (int j = 0; j < 8; ++j) {
            int ch = kt * 32 + hi * 8 + j;
            float sc_ = scl[0][ch], sh_ = shf[0][ch];
            oa[j] = f2b(fmaxf(b2f(ia[j]) * sc_ + sh_, 0.f));
            ob[j] = f2b(fmaxf(b2f(ib[j]) * sc_ + sh_, 0.f));
        }
        bvA[kt] = oa;
        bvB[kt] = ob;
    }

    unsigned pwA[8][2], pwB[8][2];

    for (int g = 1; g < 3; ++g) {
#pragma unroll
        for (int ch = 0; ch < 2; ++ch) {
            f32x4 aA[4], aB[4];
#pragma unroll
            for (int cc = 0; cc < 4; ++cc) {
                aA[cc] = (f32x4){0.f, 0.f, 0.f, 0.f};
                aB[cc] = (f32x4){0.f, 0.f, 0.f, 0.f};
            }
#pragma unroll
            for (int kt = 0; kt < 4; ++kt) {
                bf16x8 wv[4];
#pragma unroll
                for (int cc = 0; cc < 4; ++cc)
                    wv[cc] = *(const bf16x8*)(wbuf + ((((ch * 4 + cc) * 4) + kt) * 64 + l) * 8);
#pragma unroll
                for (int cc = 0; cc < 4; ++cc) {
                    aA[cc] = MFMA16(wv[cc], bvA[kt], aA[cc]);
                    aB[cc] = MFMA16(wv[cc], bvB[kt], aB[cc]);
                }
            }
#pragma unroll
            for (int cc = 0; cc < 4; ++cc) {
                int ct = ch * 4 + cc;
                int c0 = ct * 16 + hi * 4;
                float4 s4 = *(const float4*)&scl[g][c0];
                float4 h4 = *(const float4*)&shf[g][c0];
                pwA[ct][0] = packbf(fmaxf(aA[cc][0] * s4.x + h4.x, 0.f),
                                    fmaxf(aA[cc][1] * s4.y + h4.y, 0.f));
                pwA[ct][1] = packbf(fmaxf(aA[cc][2] * s4.z + h4.z, 0.f),
                                    fmaxf(aA[cc][3] * s4.w + h4.w, 0.f));
                pwB[ct][0] = packbf(fmaxf(aB[cc][0] * s4.x + h4.x, 0.f),
                                    fmaxf(aB[cc][1] * s4.y + h4.y, 0.f));
                pwB[ct][1] = packbf(fmaxf(aB[cc][2] * s4.z + h4.z, 0.f),
                                    fmaxf(aB[cc][3] * s4.w + h4.w, 0.f));
            }
        }
        __syncthreads();
        if (g < 2) stage_lds(Wt + (g + 1) * 16384, wbuf, w, l, 8);  // g=1 -> Wm1
        else       stage_lds(Wt + 49152, wbuf, w, l, 4);            // g=2 -> Wm2 (16KB)

        {
            int h2 = hi >> 1, h1 = hi & 1;
#pragma unroll
            for (int kt = 0; kt < 4; ++kt) {
                unsigned nwA[4], nwB[4];
#pragma unroll
                for (int jp = 0; jp < 4; ++jp) {
                    int srcl = (2 * h1 + (jp >> 1)) * 16 + lr;
                    unsigned veA = (unsigned)__shfl((int)pwA[2 * kt][jp & 1], srcl);
                    unsigned voA = (unsigned)__shfl((int)pwA[2 * kt + 1][jp & 1], srcl);
                    unsigned veB = (unsigned)__shfl((int)pwB[2 * kt][jp & 1], srcl);
                    unsigned voB = (unsigned)__shfl((int)pwB[2 * kt + 1][jp & 1], srcl);
                    nwA[jp] = h2 ? voA : veA;
                    nwB[jp] = h2 ? voB : veB;
                }
                u32x4 uqA = (u32x4){nwA[0], nwA[1], nwA[2], nwA[3]};
                u32x4 uqB = (u32x4){nwB[0], nwB[1], nwB[2], nwB[3]};
                bvA[kt] = __builtin_bit_cast(bf16x8, uqA);
                bvB[kt] = __builtin_bit_cast(bf16x8, uqB);
            }
        }
        __syncthreads();
    }

    // ---- G4: h @ Wm2 + bm2 -> out ----
#pragma unroll
    for (int ct = 0; ct < 4; ++ct) {
        f32x4 aA = (f32x4){0.f, 0.f, 0.f, 0.f};
        f32x4 aB = (f32x4){0.f, 0.f, 0.f, 0.f};
#pragma unroll
        for (int kt = 0; kt < 4; ++kt) {
            bf16x8 wv = *(const bf16x8*)(wbuf + ((ct * 4 + kt) * 64 + l) * 8);
            aA = MFMA16(bvA[kt], wv, aA);
            aB = MFMA16(bvB[kt], wv, aB);
        }
        float bias = bm2s[ct * 16 + lr];
#pragma unroll
        for (int rr = 0; rr < 4; ++rr) {
            size_t growA = node0 + hi * 4 + rr;
            size_t growB = node0 + 16 + hi * 4 + rr;
            if (growA < NNODES) out[growA * 64 + ct * 16 + lr] = aA[rr] + bias;
            if (growB < NNODES) out[growB * 64 + ct * 16 + lr] = aB[rr] + bias;
        }
    }
}

// ---------------- launch ----------------
extern "C" void kernel_launch(void* const* d_in, const int* in_sizes, int n_in,
                              void* d_out, int out_size, void* d_ws, size_t ws_size,
                              hipStream_t stream) {
    const float* x     = (const float*)d_in[0];
    const int*   ei    = (const int*)d_in[1];
    const float* W1    = (const float*)d_in[2];
    const float* gamma = (const float*)d_in[4];
    const float* beta  = (const float*)d_in[5];
    const float* W2    = (const float*)d_in[6];
    const float* b2    = (const float*)d_in[7];
    const float* Wm1   = (const float*)d_in[8];
    const float* bm1   = (const float*)d_in[9];
    const float* Wm2   = (const float*)d_in[10];
    const float* bm2   = (const float*)d_in[11];
    float* out = (float*)d_out;

    char* ws = (char*)d_ws;
    short* xb    = (short*)ws;                           // (N+1)*128 bf16 (last row zeros)
    short* bufb  = xb + (size_t)(NNODES + 1) * 128;      // (N+128)*128 bf16 (holds u)
    short* Wt    = bufb + (size_t)(NNODES + 128) * 128;  // 57344 bf16 packed fragments
    float* stats = (float*)(Wt + 57344);                 // 256 f32
    int* rowptr  = (int*)(stats + 256);                  // N+1
    int* pos     = rowptr + (NNODES + 1);                // N (histogram, then fill cursors)
    int* elist   = pos + NNODES;                         // E
    int* bsums   = elist + NEDGES;                       // 128

    int gE = (NEDGES + 255) / 256;
    int gPrep = ((NNODES + 1) * 16 + 255) / 256;

    k_prep<<<gPrep, 256, 0, stream>>>(x, W1, W2, Wm1, Wm2, xb, Wt, pos, stats);
    k_hist<<<gE, 256, 0, stream>>>(ei, pos);
    k_scan1<<<SCAN_NB, 256, 0, stream>>>(pos, bsums);
    k_scan23<<<SCAN_NB, 256, 0, stream>>>(pos, bsums, rowptr, pos);
    k_fill<<<gE, 256, 0, stream>>>(ei, pos, elist);

    int gAgg = (NNODES + 63) / 64;
    k_aggstats<<<gAgg, 512, 0, stream>>>(xb, rowptr, elist, Wt, bufb, stats);

    int nblkM = (NNODES + 127) / 128;
    k_mlp<<<nblkM, 256, 0, stream>>>(bufb, stats, gamma, beta, Wt, b2, bm1, bm2, out);
}